// Round 4
// baseline (1263.126 us; speedup 1.0000x reference)
//
#include <hip/hip_runtime.h>
#include <hip/hip_bf16.h>

#define B_ 2
#define S_ 2048
#define D_ 2048
#define H_ 16
#define HD_ 128
#define M_ (B_*S_)                 // 4096
#define BSD ((size_t)B_*S_*D_)     // 8388608 elements per output tensor

typedef short bf16x8 __attribute__((ext_vector_type(8)));   // 8 bf16 = 4 VGPRs
typedef float floatx4 __attribute__((ext_vector_type(4)));
typedef __hip_bfloat16 bf16;

union cv8 { bf16 h[8]; uint4 u; bf16x8 v; };

__device__ inline cv8 cvt8(const float4 a, const float4 b) {
    cv8 c;
    c.h[0] = __float2bfloat16(a.x); c.h[1] = __float2bfloat16(a.y);
    c.h[2] = __float2bfloat16(a.z); c.h[3] = __float2bfloat16(a.w);
    c.h[4] = __float2bfloat16(b.x); c.h[5] = __float2bfloat16(b.y);
    c.h[6] = __float2bfloat16(b.z); c.h[7] = __float2bfloat16(b.w);
    return c;
}

// ---------------- GEMM: C[M,N] = A[M,K] @ W[K,N] (fp32 in/out, bf16 MFMA) --
// 64x64 block tile, 4 waves in 2x2, each wave 32x32 via 2x2 of 16x16x32 MFMA.
__global__ __launch_bounds__(256) void gemm_f32(
    const float* __restrict__ A, const float* __restrict__ W,
    float* __restrict__ C, int M, int N, int K)
{
    __shared__ __align__(16) bf16 As[64][32];   // A tile, row-major (bf16)
    __shared__ __align__(16) bf16 Bs[64][32];   // W tile TRANSPOSED: Bs[n][k]
    const int m0 = blockIdx.x * 64;
    const int n0 = blockIdx.y * 64;
    const int tid = threadIdx.x;
    const int lane = tid & 63;
    const int w = tid >> 6;
    const int quad = lane >> 4;
    const int l16 = lane & 15;
    const int wrow = (w >> 1) * 32;
    const int wcol = (w & 1) * 32;

    floatx4 acc[2][2] = {};

    const int ar = tid >> 2;          // 0..63
    const int ac = (tid & 3) * 8;     // 0,8,16,24
    const int br = tid >> 3;          // 0..31  (k within tile)
    const int bc = (tid & 7) * 8;     // 0..56  (n within tile)

    for (int kt = 0; kt < K; kt += 32) {
        // stage A: 8 fp32 -> 8 bf16 -> one 16B LDS write
        {
            const float* ap = &A[(size_t)(m0 + ar) * K + kt + ac];
            cv8 c = cvt8(*(const float4*)ap, *(const float4*)(ap + 4));
            *(uint4*)&As[ar][ac] = c.u;
        }
        // stage W transposed: coalesced fp32 reads, scalar bf16 LDS writes
        {
            const float* wp = &W[(size_t)(kt + br) * N + n0 + bc];
            cv8 c = cvt8(*(const float4*)wp, *(const float4*)(wp + 4));
            #pragma unroll
            for (int i = 0; i < 8; ++i) Bs[bc + i][br] = c.h[i];
        }
        __syncthreads();

        bf16x8 af[2], bfr[2];
        #pragma unroll
        for (int t = 0; t < 2; ++t) {
            af[t]  = *(const bf16x8*)&As[wrow + t*16 + l16][quad*8];
            bfr[t] = *(const bf16x8*)&Bs[wcol + t*16 + l16][quad*8];
        }
        #pragma unroll
        for (int mt = 0; mt < 2; ++mt)
            #pragma unroll
            for (int nt = 0; nt < 2; ++nt)
                acc[mt][nt] = __builtin_amdgcn_mfma_f32_16x16x32_bf16(
                    af[mt], bfr[nt], acc[mt][nt], 0, 0, 0);
        __syncthreads();
    }

    #pragma unroll
    for (int mt = 0; mt < 2; ++mt)
        #pragma unroll
        for (int nt = 0; nt < 2; ++nt)
            #pragma unroll
            for (int r = 0; r < 4; ++r) {
                int row = m0 + wrow + mt*16 + quad*4 + r;   // C row = quad*4+reg
                int col = n0 + wcol + nt*16 + l16;          // C col = lane&15
                C[(size_t)row * N + col] = acc[mt][nt][r];
            }
}

// ---------------- RoPE (in-place on q and k, fp32) --------------------------
// Each thread owns one (d, d+64) pair -> in-place safe.
__global__ __launch_bounds__(256) void rope_kernel(
    float* __restrict__ q, float* __restrict__ k,
    const float* __restrict__ cf, const float* __restrict__ sf,
    const int* __restrict__ pos)
{
    const int PAIRS = B_*S_*H_*(HD_/2);   // 4194304
    int idx = blockIdx.x * 256 + threadIdx.x;
    float* t = q;
    if (idx >= PAIRS) { t = k; idx -= PAIRS; }
    const int d  = idx & 63;
    const int h  = (idx >> 6) & (H_-1);
    const int bs = idx >> 10;             // b*S + s
    const int p  = pos[bs];
    const float c1 = cf[p*HD_ + d];
    const float s1 = sf[p*HD_ + d];
    const float c2 = cf[p*HD_ + d + 64];
    const float s2 = sf[p*HD_ + d + 64];
    const size_t base = (size_t)bs * D_ + h*HD_ + d;
    const float t1 = t[base];
    const float t2 = t[base + 64];
    t[base]      = t1*c1 - t2*s1;
    t[base + 64] = t2*c2 + t1*s2;
}

// ---------------- Flash attention (causal, online softmax) -----------------
// Block: (q-tile of 64, one (b,h)). 4 waves x 16 q-rows. K-tiles of 32.
// qg and og may ALIAS (in-place: attn-out overwrites Q). Each block reads
// exactly the rows/features it writes; Q is consumed into registers before
// the K-loop, og stores happen after it. No __restrict__ on qg/og.
__global__ __launch_bounds__(256) void flash_attn(
    const float* qg, const float* __restrict__ kg,
    const float* __restrict__ vg, float* og)
{
    __shared__ __align__(16) bf16 Ks[32][128];     // K tile [krow][feat]
    __shared__ __align__(16) bf16 Vt[128][32];     // V tile transposed [feat][krow]
    __shared__ __align__(16) bf16 Ps[4][16][32];   // per-wave P (C->A layout hop)

    const int q0 = blockIdx.x * 64;
    const int bh = blockIdx.y;
    const int b = bh >> 4, h = bh & (H_-1);
    const int tid = threadIdx.x, lane = tid & 63, w = tid >> 6;
    const int quad = lane >> 4, l16 = lane & 15;

    // Q fragments for this wave's 16 rows: A[m=lane&15][k=quad*8+j]
    const int qrow = q0 + w*16 + l16;
    const float* qptr = qg + ((size_t)(b*S_ + qrow)*H_ + h)*HD_;
    bf16x8 qf[4];
    #pragma unroll
    for (int c = 0; c < 4; ++c) {
        const float* qp = qptr + c*32 + quad*8;
        cv8 cv = cvt8(*(const float4*)qp, *(const float4*)(qp + 4));
        qf[c] = cv.v;
    }

    floatx4 acc_o[8] = {};
    float m_run[4], l_run[4];
    #pragma unroll
    for (int r = 0; r < 4; ++r) { m_run[r] = -30000.0f; l_run[r] = 0.f; }

    const int sr  = tid >> 3;          // 0..31 staging k-row
    const int scg = (tid & 7) * 16;    // 0..112 staging feature group

    const int ktmax = (q0 + 63) >> 5;
    for (int kt = 0; kt <= ktmax; ++kt) {
        const int k0 = kt * 32;
        {   // stage K (direct) and V (transposed), fp32 -> bf16
            const size_t rowoff = ((size_t)(b*S_ + k0 + sr)*H_ + h)*HD_ + scg;
            const float* kp = kg + rowoff;
            cv8 kc0 = cvt8(*(const float4*)kp,     *(const float4*)(kp + 4));
            cv8 kc1 = cvt8(*(const float4*)(kp+8), *(const float4*)(kp + 12));
            *(uint4*)&Ks[sr][scg]     = kc0.u;
            *(uint4*)&Ks[sr][scg + 8] = kc1.u;
            const float* vp = vg + rowoff;
            cv8 vc0 = cvt8(*(const float4*)vp,     *(const float4*)(vp + 4));
            cv8 vc1 = cvt8(*(const float4*)(vp+8), *(const float4*)(vp + 12));
            #pragma unroll
            for (int i = 0; i < 8; ++i) { Vt[scg+i][sr] = vc0.h[i]; Vt[scg+8+i][sr] = vc1.h[i]; }
        }
        __syncthreads();

        // S = Q K^T : two 16-col chunks, K-dim = HD in 4 chunks of 32
        floatx4 sc[2] = {};
        #pragma unroll
        for (int c = 0; c < 2; ++c)
            #pragma unroll
            for (int kc = 0; kc < 4; ++kc) {
                bf16x8 kf = *(const bf16x8*)&Ks[c*16 + l16][kc*32 + quad*8];
                sc[c] = __builtin_amdgcn_mfma_f32_16x16x32_bf16(qf[kc], kf, sc[c], 0, 0, 0);
            }

        // scale + causal mask + online softmax
        float pv[2][4], mt_[4];
        #pragma unroll
        for (int r = 0; r < 4; ++r) mt_[r] = -30000.0f;
        #pragma unroll
        for (int c = 0; c < 2; ++c) {
            const int kcol = k0 + c*16 + l16;
            #pragma unroll
            for (int r = 0; r < 4; ++r) {
                const int qr = q0 + w*16 + quad*4 + r;
                float s = sc[c][r] * 0.08838834764831845f;   // 1/sqrt(128)
                if (kcol > qr) s = -30000.0f;
                pv[c][r] = s;
                mt_[r] = fmaxf(mt_[r], s);
            }
        }
        #pragma unroll
        for (int off = 1; off < 16; off <<= 1)
            #pragma unroll
            for (int r = 0; r < 4; ++r)
                mt_[r] = fmaxf(mt_[r], __shfl_xor(mt_[r], off, 64));
        float alpha[4];
        #pragma unroll
        for (int r = 0; r < 4; ++r) {
            float mn = fmaxf(m_run[r], mt_[r]);
            alpha[r] = __expf(m_run[r] - mn);
            m_run[r] = mn;
        }
        #pragma unroll
        for (int c = 0; c < 2; ++c)
            #pragma unroll
            for (int r = 0; r < 4; ++r)
                pv[c][r] = __expf(pv[c][r] - m_run[r]);   // masked -> 0
        #pragma unroll
        for (int r = 0; r < 4; ++r) {
            float s = pv[0][r] + pv[1][r];
            #pragma unroll
            for (int off = 1; off < 16; off <<= 1)
                s += __shfl_xor(s, off, 64);
            l_run[r] = l_run[r] * alpha[r] + s;
        }
        // P: C-layout -> LDS -> A-layout (barrier forces write->read order)
        #pragma unroll
        for (int c = 0; c < 2; ++c)
            #pragma unroll
            for (int r = 0; r < 4; ++r)
                Ps[w][quad*4 + r][c*16 + l16] = __float2bfloat16(pv[c][r]);
        __syncthreads();
        #pragma unroll
        for (int n = 0; n < 8; ++n)
            #pragma unroll
            for (int r = 0; r < 4; ++r)
                acc_o[n][r] *= alpha[r];
        bf16x8 pf = *(const bf16x8*)&Ps[w][l16][quad*8];
        #pragma unroll
        for (int n = 0; n < 8; ++n) {
            bf16x8 vf = *(const bf16x8*)&Vt[n*16 + l16][quad*8];
            acc_o[n] = __builtin_amdgcn_mfma_f32_16x16x32_bf16(pf, vf, acc_o[n], 0, 0, 0);
        }
        __syncthreads();
    }

    #pragma unroll
    for (int n = 0; n < 8; ++n)
        #pragma unroll
        for (int r = 0; r < 4; ++r) {
            const int qr = q0 + w*16 + quad*4 + r;
            og[((size_t)(b*S_ + qr))*D_ + h*HD_ + n*16 + l16] = acc_o[n][r] / l_run[r];
        }
}

// ---------------------------------------------------------------------------
extern "C" void kernel_launch(void* const* d_in, const int* in_sizes, int n_in,
                              void* d_out, int out_size, void* d_ws, size_t ws_size,
                              hipStream_t stream) {
    // Reference dtypes: ALL float arrays are float32; position_ids int32.
    const float* x  = (const float*)d_in[0];
    const float* cf = (const float*)d_in[1];
    const float* sf = (const float*)d_in[2];
    const float* Wq = (const float*)d_in[3];
    const float* Wk = (const float*)d_in[4];
    const float* Wv = (const float*)d_in[5];
    const float* Wo = (const float*)d_in[6];
    const int*  pos = (const int*)d_in[7];

    float* out  = (float*)d_out;        // [B,S,D] final; interim: Q then attn
    float* kout = out + BSD;            // [B,S,H,HD] (post-RoPE)
    float* vout = out + 2*BSD;          // [B,S,H,HD]
    float* wsb  = (float*)d_ws;

    dim3 gg(M_/64, D_/64);              // 64 x 32 blocks
    // Q staged in out0 (dead until the end) -> minimal ws reliance.
    gemm_f32<<<gg, 256, 0, stream>>>(x, Wq, out,  M_, D_, D_);
    gemm_f32<<<gg, 256, 0, stream>>>(x, Wk, kout, M_, D_, D_);
    gemm_f32<<<gg, 256, 0, stream>>>(x, Wv, vout, M_, D_, D_);
    rope_kernel<<<(2*B_*S_*H_*(HD_/2))/256, 256, 0, stream>>>(out, kout, cf, sf, pos);
    // In-place: attn-out overwrites Q in out0.
    flash_attn<<<dim3(S_/64, B_*H_), 256, 0, stream>>>(out, kout, vout, out);

    // Wo GEMM, row-chunked through ws (chunk needs R*D*4 bytes; R=64 -> 512KB).
    // Chunk i reads attn rows [m0, m0+R) from out0, writes C to ws, then d2d
    // copies back over those same rows (later chunks read strictly later rows).
    // R depends only on ws_size (constant per process) -> graph-capture safe.
    int R = 64;
    while (R < M_ && (size_t)(2*R) * D_ * sizeof(float) <= ws_size) R *= 2;
    if ((size_t)R * D_ * sizeof(float) > ws_size) R = 64;  // last resort
    for (int m0 = 0; m0 < M_; m0 += R) {
        gemm_f32<<<dim3(R/64, D_/64), 256, 0, stream>>>(out + (size_t)m0*D_, Wo, wsb, R, D_, D_);
        hipMemcpyAsync(out + (size_t)m0*D_, wsb, (size_t)R*D_*sizeof(float),
                       hipMemcpyDeviceToDevice, stream);
    }
}

// Round 5
// 729.689 us; speedup vs baseline: 1.7310x; 1.7310x over previous
//
#include <hip/hip_runtime.h>
#include <hip/hip_bf16.h>

#define B_ 2
#define S_ 2048
#define D_ 2048
#define H_ 16
#define HD_ 128
#define M_ (B_*S_)                 // 4096
#define BSD ((size_t)B_*S_*D_)     // 8388608 elements per output tensor

typedef short bf16x8 __attribute__((ext_vector_type(8)));   // 8 bf16 = 4 VGPRs
typedef float floatx4 __attribute__((ext_vector_type(4)));
typedef __hip_bfloat16 bf16;

union cv8 { bf16 h[8]; uint4 u; bf16x8 v; };

__device__ inline cv8 cvt8(const float4 a, const float4 b) {
    cv8 c;
    c.h[0] = __float2bfloat16(a.x); c.h[1] = __float2bfloat16(a.y);
    c.h[2] = __float2bfloat16(a.z); c.h[3] = __float2bfloat16(a.w);
    c.h[4] = __float2bfloat16(b.x); c.h[5] = __float2bfloat16(b.y);
    c.h[6] = __float2bfloat16(b.z); c.h[7] = __float2bfloat16(b.w);
    return c;
}

// ---------------- W transpose+convert: Wt[n][k] = bf16(W[k][n]) -------------
__global__ __launch_bounds__(256) void transpose_w(
    const float* __restrict__ W, bf16* __restrict__ Wt, int N, int K)
{
    __shared__ float T[32][33];
    const int k0 = blockIdx.x * 32, n0 = blockIdx.y * 32;
    const int r = threadIdx.x >> 3, c4 = (threadIdx.x & 7) * 4;
    float4 v = *(const float4*)&W[(size_t)(k0 + r) * N + n0 + c4];
    T[r][c4+0] = v.x; T[r][c4+1] = v.y; T[r][c4+2] = v.z; T[r][c4+3] = v.w;
    __syncthreads();
    union { bf16 h[4]; uint2 u; } o;
    #pragma unroll
    for (int i = 0; i < 4; ++i) o.h[i] = __float2bfloat16(T[c4 + i][r]);
    *(uint2*)&Wt[(size_t)(n0 + r) * K + k0 + c4] = o.u;
}

// ---------------- GEMM v2: C[M,N] fp32 = A[M,K] fp32 x Wt[N,K] bf16 ---------
// 128x128 tile, BK=32, 4 waves 2x2 (wave tile 64x64 = 4x4 MFMA 16x16x32).
__global__ __launch_bounds__(256) void gemm_xw(
    const float* __restrict__ A, const bf16* __restrict__ Wt,
    float* __restrict__ C, int M, int N, int K)
{
    __shared__ __align__(16) bf16 As[128][40];   // +8 pad: frag reads 2-way free
    __shared__ __align__(16) bf16 Bs[128][40];   // Bs[n][k]
    const int m0 = blockIdx.x * 128, n0 = blockIdx.y * 128;
    const int tid = threadIdx.x, lane = tid & 63, w = tid >> 6;
    const int quad = lane >> 4, l16 = lane & 15;
    const int wrow = (w >> 1) * 64, wcol = (w & 1) * 64;

    floatx4 acc[4][4] = {};

    const int arow = tid >> 2;        // 0..63
    const int acol = (tid & 3) * 8;   // 0,8,16,24

    for (int kt = 0; kt < K; kt += 32) {
        #pragma unroll
        for (int p = 0; p < 2; ++p) {
            const int r = p*64 + arow;
            const float* ap = &A[(size_t)(m0 + r) * K + kt + acol];
            cv8 ca = cvt8(*(const float4*)ap, *(const float4*)(ap + 4));
            *(uint4*)&As[r][acol] = ca.u;
            const bf16* bp = &Wt[(size_t)(n0 + r) * K + kt + acol];
            *(uint4*)&Bs[r][acol] = *(const uint4*)bp;
        }
        __syncthreads();

        bf16x8 af[4], bfr[4];
        #pragma unroll
        for (int t = 0; t < 4; ++t) {
            af[t]  = *(const bf16x8*)&As[wrow + t*16 + l16][quad*8];
            bfr[t] = *(const bf16x8*)&Bs[wcol + t*16 + l16][quad*8];
        }
        #pragma unroll
        for (int mt = 0; mt < 4; ++mt)
            #pragma unroll
            for (int nt = 0; nt < 4; ++nt)
                acc[mt][nt] = __builtin_amdgcn_mfma_f32_16x16x32_bf16(
                    af[mt], bfr[nt], acc[mt][nt], 0, 0, 0);
        __syncthreads();
    }

    #pragma unroll
    for (int mt = 0; mt < 4; ++mt)
        #pragma unroll
        for (int nt = 0; nt < 4; ++nt)
            #pragma unroll
            for (int r = 0; r < 4; ++r)
                C[(size_t)(m0 + wrow + mt*16 + quad*4 + r) * N
                  + n0 + wcol + nt*16 + l16] = acc[mt][nt][r];
}

// ---------------- GEMM v1 (fallback, small ws): inline W transpose ----------
__global__ __launch_bounds__(256) void gemm_f32(
    const float* __restrict__ A, const float* __restrict__ W,
    float* __restrict__ C, int M, int N, int K)
{
    __shared__ __align__(16) bf16 As[64][40];
    __shared__ __align__(16) bf16 Bs[64][40];
    const int m0 = blockIdx.x * 64, n0 = blockIdx.y * 64;
    const int tid = threadIdx.x, lane = tid & 63, w = tid >> 6;
    const int quad = lane >> 4, l16 = lane & 15;
    const int wrow = (w >> 1) * 32, wcol = (w & 1) * 32;
    floatx4 acc[2][2] = {};
    const int ar = tid >> 2, ac = (tid & 3) * 8;
    const int br = tid >> 3, bc = (tid & 7) * 8;
    for (int kt = 0; kt < K; kt += 32) {
        {
            const float* ap = &A[(size_t)(m0 + ar) * K + kt + ac];
            cv8 c = cvt8(*(const float4*)ap, *(const float4*)(ap + 4));
            *(uint4*)&As[ar][ac] = c.u;
        }
        {
            const float* wp = &W[(size_t)(kt + br) * N + n0 + bc];
            cv8 c = cvt8(*(const float4*)wp, *(const float4*)(wp + 4));
            #pragma unroll
            for (int i = 0; i < 8; ++i) Bs[bc + i][br] = c.h[i];
        }
        __syncthreads();
        bf16x8 af[2], bfr[2];
        #pragma unroll
        for (int t = 0; t < 2; ++t) {
            af[t]  = *(const bf16x8*)&As[wrow + t*16 + l16][quad*8];
            bfr[t] = *(const bf16x8*)&Bs[wcol + t*16 + l16][quad*8];
        }
        #pragma unroll
        for (int mt = 0; mt < 2; ++mt)
            #pragma unroll
            for (int nt = 0; nt < 2; ++nt)
                acc[mt][nt] = __builtin_amdgcn_mfma_f32_16x16x32_bf16(
                    af[mt], bfr[nt], acc[mt][nt], 0, 0, 0);
        __syncthreads();
    }
    #pragma unroll
    for (int mt = 0; mt < 2; ++mt)
        #pragma unroll
        for (int nt = 0; nt < 2; ++nt)
            #pragma unroll
            for (int r = 0; r < 4; ++r)
                C[(size_t)(m0 + wrow + mt*16 + quad*4 + r) * N
                  + n0 + wcol + nt*16 + l16] = acc[mt][nt][r];
}

// ---------------- RoPE (in-place on q and k, fp32) --------------------------
__global__ __launch_bounds__(256) void rope_kernel(
    float* __restrict__ q, float* __restrict__ k,
    const float* __restrict__ cf, const float* __restrict__ sf,
    const int* __restrict__ pos)
{
    const int PAIRS = B_*S_*H_*(HD_/2);
    int idx = blockIdx.x * 256 + threadIdx.x;
    float* t = q;
    if (idx >= PAIRS) { t = k; idx -= PAIRS; }
    const int d  = idx & 63;
    const int h  = (idx >> 6) & (H_-1);
    const int bs = idx >> 10;
    const int p  = pos[bs];
    const float c1 = cf[p*HD_ + d],      s1 = sf[p*HD_ + d];
    const float c2 = cf[p*HD_ + d + 64], s2 = sf[p*HD_ + d + 64];
    const size_t base = (size_t)bs * D_ + h*HD_ + d;
    const float t1 = t[base], t2 = t[base + 64];
    t[base]      = t1*c1 - t2*s1;
    t[base + 64] = t2*c2 + t1*s2;
}

// ---------------- Flash attention v2 (BK=64, padded LDS) --------------------
// qg/og may alias (in-place). 4 waves x 16 q-rows = 64-row q-tile; k-tile 64
// aligns with the causal diagonal so the mask predicate is exact everywhere.
__global__ __launch_bounds__(256) void flash_attn(
    const float* qg, const float* __restrict__ kg,
    const float* __restrict__ vg, float* og)
{
    __shared__ __align__(16) bf16 Ks[64][136];   // row 272B -> frag reads 2-way
    __shared__ __align__(16) bf16 Vt[128][72];   // row 144B -> reads/writes 2-way
    __shared__ __align__(16) bf16 Ps[4][16][72];

    const int qi = (int)gridDim.x - 1 - (int)blockIdx.x;  // heavy tiles first
    const int q0 = qi * 64;
    const int bh = blockIdx.y;
    const int b = bh >> 4, h = bh & (H_-1);
    const int tid = threadIdx.x, lane = tid & 63, w = tid >> 6;
    const int quad = lane >> 4, l16 = lane & 15;

    // Q fragments: A[m=l16][k=quad*8+j], 4 chunks over HD=128
    const int qrow = q0 + w*16 + l16;
    const float* qptr = qg + ((size_t)(b*S_ + qrow)*H_ + h)*HD_;
    bf16x8 qf[4];
    #pragma unroll
    for (int c = 0; c < 4; ++c) {
        const float* qp = qptr + c*32 + quad*8;
        cv8 cv = cvt8(*(const float4*)qp, *(const float4*)(qp + 4));
        qf[c] = cv.v;
    }

    floatx4 acc_o[8] = {};
    float m_run[4], l_run[4];
    #pragma unroll
    for (int r = 0; r < 4; ++r) { m_run[r] = -30000.0f; l_run[r] = 0.f; }

    const int ksr = tid >> 2, kscg = (tid & 3) * 32;      // K staging
    const int vk2 = (tid & 31) * 2, vf8 = (tid >> 5) * 8; // V staging

    for (int kt = 0; kt <= qi; ++kt) {
        const int k0 = kt * 64;
        {   // stage K [64][128] fp32 -> bf16, vector b128 writes
            const float* kp = kg + ((size_t)(b*S_ + k0 + ksr)*H_ + h)*HD_ + kscg;
            #pragma unroll
            for (int j = 0; j < 4; ++j) {
                cv8 c = cvt8(*(const float4*)(kp + j*8), *(const float4*)(kp + j*8 + 4));
                *(uint4*)&Ks[ksr][kscg + j*8] = c.u;
            }
        }
        {   // stage V transposed: paired-row b32 writes (2-way = free)
            #pragma unroll
            for (int p = 0; p < 2; ++p) {
                const int f = vf8 + p*64;
                const float* v0p = vg + ((size_t)(b*S_ + k0 + vk2)*H_ + h)*HD_ + f;
                const float* v1p = v0p + D_;
                cv8 c0 = cvt8(*(const float4*)v0p, *(const float4*)(v0p + 4));
                cv8 c1 = cvt8(*(const float4*)v1p, *(const float4*)(v1p + 4));
                #pragma unroll
                for (int i = 0; i < 8; ++i) {
                    union { bf16 h2[2]; unsigned u; } pk;
                    pk.h2[0] = c0.h[i]; pk.h2[1] = c1.h[i];
                    *(unsigned*)&Vt[f + i][vk2] = pk.u;
                }
            }
        }
        __syncthreads();

        // S = Q K^T : 4 col-chunks x 4 k-chunks
        floatx4 sc[4] = {};
        #pragma unroll
        for (int c = 0; c < 4; ++c)
            #pragma unroll
            for (int kc = 0; kc < 4; ++kc) {
                bf16x8 kf = *(const bf16x8*)&Ks[c*16 + l16][kc*32 + quad*8];
                sc[c] = __builtin_amdgcn_mfma_f32_16x16x32_bf16(qf[kc], kf, sc[c], 0, 0, 0);
            }

        // scale + causal mask (false everywhere except diagonal tile) + softmax
        float pv[4][4], mt_[4];
        #pragma unroll
        for (int r = 0; r < 4; ++r) mt_[r] = -30000.0f;
        #pragma unroll
        for (int c = 0; c < 4; ++c) {
            const int kcol = k0 + c*16 + l16;
            #pragma unroll
            for (int r = 0; r < 4; ++r) {
                const int qr = q0 + w*16 + quad*4 + r;
                float s = sc[c][r] * 0.08838834764831845f;
                if (kcol > qr) s = -30000.0f;
                pv[c][r] = s;
                mt_[r] = fmaxf(mt_[r], s);
            }
        }
        #pragma unroll
        for (int off = 1; off < 16; off <<= 1)
            #pragma unroll
            for (int r = 0; r < 4; ++r)
                mt_[r] = fmaxf(mt_[r], __shfl_xor(mt_[r], off, 64));
        float alpha[4];
        #pragma unroll
        for (int r = 0; r < 4; ++r) {
            float mn = fmaxf(m_run[r], mt_[r]);
            alpha[r] = __expf(m_run[r] - mn);
            m_run[r] = mn;
        }
        #pragma unroll
        for (int c = 0; c < 4; ++c)
            #pragma unroll
            for (int r = 0; r < 4; ++r)
                pv[c][r] = __expf(pv[c][r] - m_run[r]);
        #pragma unroll
        for (int r = 0; r < 4; ++r) {
            float s = pv[0][r] + pv[1][r] + pv[2][r] + pv[3][r];
            #pragma unroll
            for (int off = 1; off < 16; off <<= 1)
                s += __shfl_xor(s, off, 64);
            l_run[r] = l_run[r] * alpha[r] + s;
        }
        #pragma unroll
        for (int c = 0; c < 4; ++c)
            #pragma unroll
            for (int r = 0; r < 4; ++r)
                Ps[w][quad*4 + r][c*16 + l16] = __float2bfloat16(pv[c][r]);
        __syncthreads();   // Ps write -> read ordering

        #pragma unroll
        for (int n = 0; n < 8; ++n)
            #pragma unroll
            for (int r = 0; r < 4; ++r)
                acc_o[n][r] *= alpha[r];
        bf16x8 pf[2];
        #pragma unroll
        for (int kc2 = 0; kc2 < 2; ++kc2)
            pf[kc2] = *(const bf16x8*)&Ps[w][l16][kc2*32 + quad*8];
        #pragma unroll
        for (int n = 0; n < 8; ++n)
            #pragma unroll
            for (int kc2 = 0; kc2 < 2; ++kc2) {
                bf16x8 vf = *(const bf16x8*)&Vt[n*16 + l16][kc2*32 + quad*8];
                acc_o[n] = __builtin_amdgcn_mfma_f32_16x16x32_bf16(pf[kc2], vf, acc_o[n], 0, 0, 0);
            }
        __syncthreads();   // protect Ks/Vt from next iter's staging
    }

    #pragma unroll
    for (int n = 0; n < 8; ++n)
        #pragma unroll
        for (int r = 0; r < 4; ++r) {
            const int qr = q0 + w*16 + quad*4 + r;
            og[((size_t)(b*S_ + qr))*D_ + h*HD_ + n*16 + l16] = acc_o[n][r] / l_run[r];
        }
}

// ---------------------------------------------------------------------------
extern "C" void kernel_launch(void* const* d_in, const int* in_sizes, int n_in,
                              void* d_out, int out_size, void* d_ws, size_t ws_size,
                              hipStream_t stream) {
    const float* x  = (const float*)d_in[0];
    const float* cf = (const float*)d_in[1];
    const float* sf = (const float*)d_in[2];
    const float* Wq = (const float*)d_in[3];
    const float* Wk = (const float*)d_in[4];
    const float* Wv = (const float*)d_in[5];
    const float* Wo = (const float*)d_in[6];
    const int*  pos = (const int*)d_in[7];

    float* out  = (float*)d_out;        // final; interim: Q then attn-out
    float* kout = out + BSD;
    float* vout = out + 2*BSD;

    const size_t WT_BYTES = (size_t)D_ * D_ * sizeof(bf16);   // 8 MB
    const bool big = ws_size >= WT_BYTES + (size_t)128 * D_ * sizeof(float);

    if (big) {
        bf16*  wt  = (bf16*)d_ws;
        float* cws = (float*)((char*)d_ws + WT_BYTES);
        const size_t crem = ws_size - WT_BYTES;
        dim3 tg(D_/32, D_/32), gg(M_/128, D_/128);
        transpose_w<<<tg, 256, 0, stream>>>(Wq, wt, D_, D_);
        gemm_xw<<<gg, 256, 0, stream>>>(x, wt, out,  M_, D_, D_);
        transpose_w<<<tg, 256, 0, stream>>>(Wk, wt, D_, D_);
        gemm_xw<<<gg, 256, 0, stream>>>(x, wt, kout, M_, D_, D_);
        transpose_w<<<tg, 256, 0, stream>>>(Wv, wt, D_, D_);
        gemm_xw<<<gg, 256, 0, stream>>>(x, wt, vout, M_, D_, D_);
        rope_kernel<<<(2*B_*S_*H_*(HD_/2))/256, 256, 0, stream>>>(out, kout, cf, sf, pos);
        flash_attn<<<dim3(S_/64, B_*H_), 256, 0, stream>>>(out, kout, vout, out);
        transpose_w<<<tg, 256, 0, stream>>>(Wo, wt, D_, D_);
        int R = 128;
        while (R < M_ && (size_t)(2*R) * D_ * sizeof(float) <= crem) R *= 2;
        for (int m0 = 0; m0 < M_; m0 += R) {
            gemm_xw<<<dim3(R/128, D_/128), 256, 0, stream>>>(out + (size_t)m0*D_, wt, cws, R, D_, D_);
            hipMemcpyAsync(out + (size_t)m0*D_, cws, (size_t)R*D_*sizeof(float),
                           hipMemcpyDeviceToDevice, stream);
        }
    } else {
        float* wsb = (float*)d_ws;
        dim3 gg(M_/64, D_/64);
        gemm_f32<<<gg, 256, 0, stream>>>(x, Wq, out,  M_, D_, D_);
        gemm_f32<<<gg, 256, 0, stream>>>(x, Wk, kout, M_, D_, D_);
        gemm_f32<<<gg, 256, 0, stream>>>(x, Wv, vout, M_, D_, D_);
        rope_kernel<<<(2*B_*S_*H_*(HD_/2))/256, 256, 0, stream>>>(out, kout, cf, sf, pos);
        flash_attn<<<dim3(S_/64, B_*H_), 256, 0, stream>>>(out, kout, vout, out);
        int R = 64;
        while (R < M_ && (size_t)(2*R) * D_ * sizeof(float) <= ws_size) R *= 2;
        if ((size_t)R * D_ * sizeof(float) > ws_size) R = 64;
        for (int m0 = 0; m0 < M_; m0 += R) {
            gemm_f32<<<dim3(R/64, D_/64), 256, 0, stream>>>(out + (size_t)m0*D_, Wo, wsb, R, D_, D_);
            hipMemcpyAsync(out + (size_t)m0*D_, wsb, (size_t)R*D_*sizeof(float),
                           hipMemcpyDeviceToDevice, stream);
        }
    }
}